// Round 9
// baseline (234.715 us; speedup 1.0000x reference)
//
#include <hip/hip_runtime.h>
#include <math.h>

#define NTOK 96
#define EMBED 128
#define HEADS 4
#define HD 32
#define NROW (NTOK*NTOK)     // 9216
#define YT 8
#define NYT (NTOK/YT)        // 12

// ---- K1: pT[(y*96+x)] = row(x,y) of x@W+b ; per-(row,head) {mu,rstd,Sg2,Sgb} ----
// 2304 blocks x 128 threads, 4 rows per block
__global__ __launch_bounds__(128) void k_proj(
    const float* __restrict__ x, const float* __restrict__ W,
    const float* __restrict__ b, const float* __restrict__ ln_g,
    const float* __restrict__ ln_b,
    float* __restrict__ pT, float4* __restrict__ murT) {
  const int r0 = blockIdx.x * 4;         // global row = X*96 + y
  const int X  = r0 / NTOK;
  const int y0 = r0 % NTOK;
  const int e  = threadIdx.x;            // 0..127
  __shared__ float xt[EMBED][4];
  #pragma unroll
  for (int k = 0; k < 4; ++k)
    xt[e][k] = x[(size_t)(r0 + k) * EMBED + e];
  __syncthreads();

  const float bias = b[e];
  float a0 = bias, a1 = bias, a2 = bias, a3 = bias;
  #pragma unroll 8
  for (int i = 0; i < EMBED; ++i) {
    const float wv = W[(size_t)i * EMBED + e];
    const float4 c = *(const float4*)&xt[i][0];
    a0 = fmaf(wv, c.x, a0); a1 = fmaf(wv, c.y, a1);
    a2 = fmaf(wv, c.z, a2); a3 = fmaf(wv, c.w, a3);
  }

  const int h = e >> 5;
  const float gl = ln_g[e & 31];
  const float bl = ln_b[e & 31];
  const float gl2 = gl * gl;
  const float gvb = gl * bl;
  float accs[4] = {a0, a1, a2, a3};
  #pragma unroll
  for (int k = 0; k < 4; ++k) {
    const float v = accs[k];
    pT[((size_t)(y0 + k) * NTOK + X) * EMBED + e] = v;
    float s1 = v, s2 = v * v, s3 = gl2 * v, s4 = gvb * v;
    #pragma unroll
    for (int m_ = 1; m_ < 32; m_ <<= 1) {
      s1 += __shfl_xor(s1, m_, 64);
      s2 += __shfl_xor(s2, m_, 64);
      s3 += __shfl_xor(s3, m_, 64);
      s4 += __shfl_xor(s4, m_, 64);
    }
    if ((e & 31) == 0) {
      const float mu = s1 * (1.f / HD);
      const float var = fmaxf(s2 * (1.f / HD) - mu * mu, 0.f);
      float4 o; o.x = mu; o.y = rsqrtf(var + 1e-5f); o.z = s3; o.w = s4;
      murT[((size_t)(y0 + k) * NTOK + X) * HEADS + h] = o;
    }
  }
}

#define PR_QUAD(E4, F4, G2, T4) \
  T4.x = E4.x * F4.x; sraw = fmaf(G2.x, T4.x, sraw); m += T4.x; q = fmaf(T4.x, T4.x, q); \
  T4.y = E4.y * F4.y; sraw = fmaf(G2.y, T4.y, sraw); m += T4.y; q = fmaf(T4.y, T4.y, q); \
  T4.z = E4.z * F4.z; sraw = fmaf(G2.z, T4.z, sraw); m += T4.z; q = fmaf(T4.z, T4.z, q); \
  T4.w = E4.w * F4.w; sraw = fmaf(G2.w, T4.w, sraw); m += T4.w; q = fmaf(T4.w, T4.w, q);

#define AGG_QUAD(A4, T4) \
  A4.x = fmaf(w, T4.x, A4.x); A4.y = fmaf(w, T4.y, A4.y); \
  A4.z = fmaf(w, T4.z, A4.z); A4.w = fmaf(w, T4.w, A4.w);

#define RED_QUAD(A4, MASK) \
  A4.x += __shfl_xor(A4.x, MASK, 64); A4.y += __shfl_xor(A4.y, MASK, 64); \
  A4.z += __shfl_xor(A4.z, MASK, 64); A4.w += __shfl_xor(A4.w, MASK, 64);

// ---- K2: attention + product-LN aggregation, one head per block ----
// 4608 blocks (X fastest; then yt:12, h:4) x 256 threads = (y:8, ds:2, da:16)
// No online max: scores are provably bounded by SB (LN'd rows), exp(sc-SB) safe.
__global__ __launch_bounds__(256, 8) void k_attn(
    const float* __restrict__ pT, const float4* __restrict__ murT,
    const float* __restrict__ ln_g, const float* __restrict__ ln_b,
    float* __restrict__ agg) {
  const int bid = blockIdx.x;
  const int X   = bid % NTOK;
  const int t2i = bid / NTOK;            // 0..47
  const int y0  = (t2i % NYT) * YT;
  const int H   = t2i / NYT;

  const int tid = threadIdx.x;
  const int y   = tid >> 5;            // 0..7
  const int ds  = (tid >> 4) & 1;      // d-half
  const int da  = tid & 15;            // a-slice
  const int yy  = y0 + y;
  const int eoff = ds * 16;

  __shared__ float e_sm[NTOK][36];     // 13.8 KB
  __shared__ float4 mur_sm[NTOK];      // 1.5 KB

  // stage e-side (head slice of rows (a*96+X))
  #pragma unroll
  for (int i = 0; i < 3; ++i) {
    const int g = tid + i * 256;       // 0..767
    const int a = g >> 3, qq = g & 7;
    *(float4*)&e_sm[a][qq * 4] =
        *(const float4*)&pT[((size_t)a * NTOK + X) * EMBED + H * HD + qq * 4];
  }
  if (tid < NTOK)
    mur_sm[tid] = murT[((size_t)tid * NTOK + X) * HEADS + H];

  // LN constants: T2=sum g^2, Vb=sum g*b, Wb=sum b^2, Mg2=max g^2
  const float glx = ln_g[tid & 31];
  const float blx = ln_b[tid & 31];
  float T2c = glx * glx, Vbc = glx * blx, Wbc = blx * blx, Mg2 = glx * glx;
  #pragma unroll
  for (int m_ = 1; m_ < 32; m_ <<= 1) {
    T2c += __shfl_xor(T2c, m_, 64);
    Vbc += __shfl_xor(Vbc, m_, 64);
    Wbc += __shfl_xor(Wbc, m_, 64);
    Mg2 = fmaxf(Mg2, __shfl_xor(Mg2, m_, 64));
  }
  // score bound: |sc| <= (64*Mg2 + 2*Wb) / sqrt(32)
  const float SB = (64.f * Mg2 + 2.f * Wbc) * 0.17677669529663687f;

  // g^2 weights for this lane's d-range
  const float4 ga0 = *(const float4*)&ln_g[eoff];
  const float4 ga1 = *(const float4*)&ln_g[eoff + 4];
  const float4 ga2 = *(const float4*)&ln_g[eoff + 8];
  const float4 ga3 = *(const float4*)&ln_g[eoff + 12];
  float4 g2q0, g2q1, g2q2, g2q3;
  g2q0.x = ga0.x*ga0.x; g2q0.y = ga0.y*ga0.y; g2q0.z = ga0.z*ga0.z; g2q0.w = ga0.w*ga0.w;
  g2q1.x = ga1.x*ga1.x; g2q1.y = ga1.y*ga1.y; g2q1.z = ga1.z*ga1.z; g2q1.w = ga1.w*ga1.w;
  g2q2.x = ga2.x*ga2.x; g2q2.y = ga2.y*ga2.y; g2q2.z = ga2.z*ga2.z; g2q2.w = ga2.w*ga2.w;
  g2q3.x = ga3.x*ga3.x; g2q3.y = ga3.y*ga3.y; g2q3.z = ga3.z*ga3.z; g2q3.w = ga3.w*ga3.w;
  __syncthreads();

  const float* fbase = pT + (size_t)yy * NTOK * EMBED + H * HD + eoff;
  const float4* mfb  = murT + (size_t)yy * NTOK * HEADS + H;

  float4 acc0 = {0,0,0,0}, acc1 = {0,0,0,0}, acc2 = {0,0,0,0}, acc3 = {0,0,0,0};
  float den = 0.f, cc = 0.f;

  #pragma unroll 2
  for (int ia = 0; ia < 6; ++ia) {
    const int a = ia * 16 + da;
    const float4* fp = (const float4*)(fbase + (size_t)a * EMBED);
    const float4 f0 = fp[0], f1 = fp[1], f2 = fp[2], f3 = fp[3];
    const float4 mrF = mfb[(size_t)a * HEADS];
    const float4 mrE = mur_sm[a];
    const float4 e0 = *(const float4*)&e_sm[a][eoff];
    const float4 e1 = *(const float4*)&e_sm[a][eoff + 4];
    const float4 e2 = *(const float4*)&e_sm[a][eoff + 8];
    const float4 e3 = *(const float4*)&e_sm[a][eoff + 12];

    float sraw = 0.f, m = 0.f, q = 0.f;
    float4 t0, t1, t2, t3;
    PR_QUAD(e0, f0, g2q0, t0);
    PR_QUAD(e1, f1, g2q1, t1);
    PR_QUAD(e2, f2, g2q2, t2);
    PR_QUAD(e3, f3, g2q3, t3);

    // combine d-halves (xor ds bit)
    sraw += __shfl_xor(sraw, 16, 64);
    m    += __shfl_xor(m,    16, 64);
    q    += __shfl_xor(q,    16, 64);

    // LN'd score from raw moments
    const float muE = mrE.x, rE = mrE.y, Sg2E = mrE.z, SgbE = mrE.w;
    const float muF = mrF.x, rF = mrF.y, Sg2F = mrF.z, SgbF = mrF.w;
    const float inner = sraw - muF * Sg2E - muE * Sg2F + muE * muF * T2c;
    const float sfull = rE * rF * inner
                      + rE * (SgbE - muE * Vbc)
                      + rF * (SgbF - muF * Vbc) + Wbc;
    const float sc = sfull * 0.17677669529663687f;   // 1/sqrt(32)

    // product-LN stats
    const float mu = m * (1.f / HD);
    const float var = fmaxf(fmaf(-mu, mu, q * (1.f / HD)), 0.f);
    const float r = rsqrtf(var + 1e-5f);

    const float ex = __expf(sc - SB);   // <= 1 by construction
    const float w = ex * r;
    den += ex;
    cc  = fmaf(w, mu, cc);
    AGG_QUAD(acc0, t0);
    AGG_QUAD(acc1, t1);
    AGG_QUAD(acc2, t2);
    AGG_QUAD(acc3, t3);
  }

  // cross-a reduction over the 16 da lanes
  #pragma unroll
  for (int mask = 1; mask <= 8; mask <<= 1) {
    den += __shfl_xor(den, mask, 64);
    cc  += __shfl_xor(cc,  mask, 64);
    RED_QUAD(acc0, mask);
    RED_QUAD(acc1, mask);
    RED_QUAD(acc2, mask);
    RED_QUAD(acc3, mask);
  }

  if (da == 0) {
    const float4 bq0 = *(const float4*)&ln_b[eoff];
    const float4 bq1 = *(const float4*)&ln_b[eoff + 4];
    const float4 bq2 = *(const float4*)&ln_b[eoff + 8];
    const float4 bq3 = *(const float4*)&ln_b[eoff + 12];
    const float inv = 1.f / den;
    float4 o0, o1, o2, o3;
    o0.x = fmaf(ga0.x, (acc0.x - cc) * inv, bq0.x);
    o0.y = fmaf(ga0.y, (acc0.y - cc) * inv, bq0.y);
    o0.z = fmaf(ga0.z, (acc0.z - cc) * inv, bq0.z);
    o0.w = fmaf(ga0.w, (acc0.w - cc) * inv, bq0.w);
    o1.x = fmaf(ga1.x, (acc1.x - cc) * inv, bq1.x);
    o1.y = fmaf(ga1.y, (acc1.y - cc) * inv, bq1.y);
    o1.z = fmaf(ga1.z, (acc1.z - cc) * inv, bq1.z);
    o1.w = fmaf(ga1.w, (acc1.w - cc) * inv, bq1.w);
    o2.x = fmaf(ga2.x, (acc2.x - cc) * inv, bq2.x);
    o2.y = fmaf(ga2.y, (acc2.y - cc) * inv, bq2.y);
    o2.z = fmaf(ga2.z, (acc2.z - cc) * inv, bq2.z);
    o2.w = fmaf(ga2.w, (acc2.w - cc) * inv, bq2.w);
    o3.x = fmaf(ga3.x, (acc3.x - cc) * inv, bq3.x);
    o3.y = fmaf(ga3.y, (acc3.y - cc) * inv, bq3.y);
    o3.z = fmaf(ga3.z, (acc3.z - cc) * inv, bq3.z);
    o3.w = fmaf(ga3.w, (acc3.w - cc) * inv, bq3.w);
    float* op = agg + ((size_t)(X * NTOK + yy)) * EMBED + H * HD + eoff;
    *(float4*)&op[0]  = o0;
    *(float4*)&op[4]  = o1;
    *(float4*)&op[8]  = o2;
    *(float4*)&op[12] = o3;
  }
}

// ---- K3: out = LN([x, agg] @ Wf + bf) ----
// 1152 blocks x 256 threads, 8 rows per block
__global__ __launch_bounds__(256) void k_final(
    const float* __restrict__ x, const float* __restrict__ agg,
    const float* __restrict__ Wf, const float* __restrict__ bf,
    const float* __restrict__ g2, const float* __restrict__ b2,
    float* __restrict__ out) {
  const int r0 = blockIdx.x * 8;
  const int tid = threadIdx.x;
  const int e = tid & 127;
  const int rh = tid >> 7;               // rows rh*4 .. rh*4+3
  __shared__ float ct[2 * EMBED][12];    // transposed [x|agg], 12.3 KB
  __shared__ float red_sm[4][4][2];

  #pragma unroll
  for (int i = 0; i < 8; ++i) {
    const int g = tid + i * 256;         // 0..2047
    const int yl = g >> 8, col = g & 255;
    const size_t row = (size_t)(r0 + yl);
    const float v = (col < 128) ? x[row * EMBED + col]
                                : agg[row * EMBED + (col - 128)];
    ct[col][yl] = v;
  }
  __syncthreads();

  const float bias = bf[e];
  float acc4[4] = {bias, bias, bias, bias};
  #pragma unroll 8
  for (int i = 0; i < 2 * EMBED; ++i) {
    const float wv = Wf[(size_t)i * EMBED + e];
    const float4 c0 = *(const float4*)&ct[i][rh * 4];
    acc4[0] = fmaf(wv, c0.x, acc4[0]); acc4[1] = fmaf(wv, c0.y, acc4[1]);
    acc4[2] = fmaf(wv, c0.z, acc4[2]); acc4[3] = fmaf(wv, c0.w, acc4[3]);
  }

  const int wid = tid >> 6;
  #pragma unroll
  for (int k = 0; k < 4; ++k) {
    float s1 = acc4[k], s2 = acc4[k] * acc4[k];
    #pragma unroll
    for (int m_ = 1; m_ < 64; m_ <<= 1) {
      s1 += __shfl_xor(s1, m_, 64);
      s2 += __shfl_xor(s2, m_, 64);
    }
    if ((tid & 63) == 0) { red_sm[wid][k][0] = s1; red_sm[wid][k][1] = s2; }
  }
  __syncthreads();

  const float gg = g2[e], bb = b2[e];
  #pragma unroll
  for (int k = 0; k < 4; ++k) {
    const float S1 = red_sm[wid][k][0] + red_sm[wid ^ 1][k][0];
    const float S2 = red_sm[wid][k][1] + red_sm[wid ^ 1][k][1];
    const float mu = S1 * (1.f / EMBED);
    const float var = fmaxf(S2 * (1.f / EMBED) - mu * mu, 0.f);
    const float rstd = rsqrtf(var + 1e-5f);
    out[(size_t)(r0 + rh * 4 + k) * EMBED + e] = (acc4[k] - mu) * rstd * gg + bb;
  }
}

extern "C" void kernel_launch(void* const* d_in, const int* in_sizes, int n_in,
                              void* d_out, int out_size, void* d_ws, size_t ws_size,
                              hipStream_t stream) {
  const float* x    = (const float*)d_in[0];
  const float* W    = (const float*)d_in[1];
  const float* b    = (const float*)d_in[2];
  const float* ln_g = (const float*)d_in[3];
  const float* ln_b = (const float*)d_in[4];
  const float* Wf   = (const float*)d_in[5];
  const float* bf   = (const float*)d_in[6];
  const float* g2   = (const float*)d_in[7];
  const float* b2   = (const float*)d_in[8];
  float* out = (float*)d_out;

  float*  pT   = (float*)d_ws;                        // NROW*128 floats
  float4* murT = (float4*)(pT + (size_t)NROW * EMBED);// NROW*4 float4
  float*  agg  = (float*)(murT + (size_t)NROW * HEADS);

  k_proj<<<NROW / 4, 128, 0, stream>>>(x, W, b, ln_g, ln_b, pT, murT);
  k_attn<<<NTOK * NYT * HEADS, 256, 0, stream>>>(pT, murT, ln_g, ln_b, agg);
  k_final<<<NROW / 8, 256, 0, stream>>>(x, agg, Wf, bf, g2, b2, out);
}

// Round 10
// 112.475 us; speedup vs baseline: 2.0868x; 2.0868x over previous
//
#include <hip/hip_runtime.h>
#include <math.h>

#define NTOK 96
#define EMBED 128
#define HEADS 4
#define HD 32
#define NROW (NTOK*NTOK)     // 9216
#define YT 8
#define NYT (NTOK/YT)        // 12

// ---- K1: pT[(y*96+x)] = row(x,y) of x@W+b ; per-(row,head) {mu,rstd,Sg2,Sgb} ----
// 2304 blocks x 128 threads, 4 rows per block
__global__ __launch_bounds__(128) void k_proj(
    const float* __restrict__ x, const float* __restrict__ W,
    const float* __restrict__ b, const float* __restrict__ ln_g,
    const float* __restrict__ ln_b,
    float* __restrict__ pT, float4* __restrict__ murT) {
  const int r0 = blockIdx.x * 4;         // global row = X*96 + y
  const int X  = r0 / NTOK;
  const int y0 = r0 % NTOK;
  const int e  = threadIdx.x;            // 0..127
  __shared__ float xt[EMBED][4];
  #pragma unroll
  for (int k = 0; k < 4; ++k)
    xt[e][k] = x[(size_t)(r0 + k) * EMBED + e];
  __syncthreads();

  const float bias = b[e];
  float a0 = bias, a1 = bias, a2 = bias, a3 = bias;
  #pragma unroll 8
  for (int i = 0; i < EMBED; ++i) {
    const float wv = W[(size_t)i * EMBED + e];
    const float4 c = *(const float4*)&xt[i][0];
    a0 = fmaf(wv, c.x, a0); a1 = fmaf(wv, c.y, a1);
    a2 = fmaf(wv, c.z, a2); a3 = fmaf(wv, c.w, a3);
  }

  const int h = e >> 5;
  const float gl = ln_g[e & 31];
  const float bl = ln_b[e & 31];
  const float gl2 = gl * gl;
  const float gvb = gl * bl;
  float accs[4] = {a0, a1, a2, a3};
  #pragma unroll
  for (int k = 0; k < 4; ++k) {
    const float v = accs[k];
    pT[((size_t)(y0 + k) * NTOK + X) * EMBED + e] = v;
    float s1 = v, s2 = v * v, s3 = gl2 * v, s4 = gvb * v;
    #pragma unroll
    for (int m_ = 1; m_ < 32; m_ <<= 1) {
      s1 += __shfl_xor(s1, m_, 64);
      s2 += __shfl_xor(s2, m_, 64);
      s3 += __shfl_xor(s3, m_, 64);
      s4 += __shfl_xor(s4, m_, 64);
    }
    if ((e & 31) == 0) {
      const float mu = s1 * (1.f / HD);
      const float var = fmaxf(s2 * (1.f / HD) - mu * mu, 0.f);
      float4 o; o.x = mu; o.y = rsqrtf(var + 1e-5f); o.z = s3; o.w = s4;
      murT[((size_t)(y0 + k) * NTOK + X) * HEADS + h] = o;
    }
  }
}

#define PR_QUAD(E4, F4, G2, T4) \
  T4.x = E4.x * F4.x; sraw = fmaf(G2.x, T4.x, sraw); m += T4.x; q = fmaf(T4.x, T4.x, q); \
  T4.y = E4.y * F4.y; sraw = fmaf(G2.y, T4.y, sraw); m += T4.y; q = fmaf(T4.y, T4.y, q); \
  T4.z = E4.z * F4.z; sraw = fmaf(G2.z, T4.z, sraw); m += T4.z; q = fmaf(T4.z, T4.z, q); \
  T4.w = E4.w * F4.w; sraw = fmaf(G2.w, T4.w, sraw); m += T4.w; q = fmaf(T4.w, T4.w, q);

#define AGG_QUAD(A4, T4) \
  A4.x = fmaf(w, T4.x, A4.x); A4.y = fmaf(w, T4.y, A4.y); \
  A4.z = fmaf(w, T4.z, A4.z); A4.w = fmaf(w, T4.w, A4.w);

#define RED_QUAD(A4, MASK) \
  A4.x += __shfl_xor(A4.x, MASK, 64); A4.y += __shfl_xor(A4.y, MASK, 64); \
  A4.z += __shfl_xor(A4.z, MASK, 64); A4.w += __shfl_xor(A4.w, MASK, 64);

// ---- K2: attention + product-LN aggregation, one head per block ----
// 4608 blocks (X fastest; then yt:12, h:4) x 256 threads = (y:8, ds:2, da:16)
// No online max: scores are provably bounded by SB (LN'd rows), exp(sc-SB) safe.
__global__ __launch_bounds__(256) void k_attn(
    const float* __restrict__ pT, const float4* __restrict__ murT,
    const float* __restrict__ ln_g, const float* __restrict__ ln_b,
    float* __restrict__ agg) {
  const int bid = blockIdx.x;
  const int X   = bid % NTOK;
  const int t2i = bid / NTOK;            // 0..47
  const int y0  = (t2i % NYT) * YT;
  const int H   = t2i / NYT;

  const int tid = threadIdx.x;
  const int y   = tid >> 5;            // 0..7
  const int ds  = (tid >> 4) & 1;      // d-half
  const int da  = tid & 15;            // a-slice
  const int yy  = y0 + y;
  const int eoff = ds * 16;

  __shared__ float e_sm[NTOK][36];     // 13.8 KB
  __shared__ float4 mur_sm[NTOK];      // 1.5 KB

  // stage e-side (head slice of rows (a*96+X))
  #pragma unroll
  for (int i = 0; i < 3; ++i) {
    const int g = tid + i * 256;       // 0..767
    const int a = g >> 3, qq = g & 7;
    *(float4*)&e_sm[a][qq * 4] =
        *(const float4*)&pT[((size_t)a * NTOK + X) * EMBED + H * HD + qq * 4];
  }
  if (tid < NTOK)
    mur_sm[tid] = murT[((size_t)tid * NTOK + X) * HEADS + H];

  // LN constants: T2=sum g^2, Vb=sum g*b, Wb=sum b^2, Mg2=max g^2
  const float glx = ln_g[tid & 31];
  const float blx = ln_b[tid & 31];
  float T2c = glx * glx, Vbc = glx * blx, Wbc = blx * blx, Mg2 = glx * glx;
  #pragma unroll
  for (int m_ = 1; m_ < 32; m_ <<= 1) {
    T2c += __shfl_xor(T2c, m_, 64);
    Vbc += __shfl_xor(Vbc, m_, 64);
    Wbc += __shfl_xor(Wbc, m_, 64);
    Mg2 = fmaxf(Mg2, __shfl_xor(Mg2, m_, 64));
  }
  // score bound: |sc| <= (64*Mg2 + 2*Wb) / sqrt(32)
  const float SB = (64.f * Mg2 + 2.f * Wbc) * 0.17677669529663687f;

  // g^2 weights for this lane's d-range (ga NOT kept live; reloaded in epilogue)
  float4 g2q0, g2q1, g2q2, g2q3;
  {
    const float4 t0 = *(const float4*)&ln_g[eoff];
    const float4 t1 = *(const float4*)&ln_g[eoff + 4];
    const float4 t2 = *(const float4*)&ln_g[eoff + 8];
    const float4 t3 = *(const float4*)&ln_g[eoff + 12];
    g2q0.x = t0.x*t0.x; g2q0.y = t0.y*t0.y; g2q0.z = t0.z*t0.z; g2q0.w = t0.w*t0.w;
    g2q1.x = t1.x*t1.x; g2q1.y = t1.y*t1.y; g2q1.z = t1.z*t1.z; g2q1.w = t1.w*t1.w;
    g2q2.x = t2.x*t2.x; g2q2.y = t2.y*t2.y; g2q2.z = t2.z*t2.z; g2q2.w = t2.w*t2.w;
    g2q3.x = t3.x*t3.x; g2q3.y = t3.y*t3.y; g2q3.z = t3.z*t3.z; g2q3.w = t3.w*t3.w;
  }
  __syncthreads();

  const float* fbase = pT + (size_t)yy * NTOK * EMBED + H * HD + eoff;
  const float4* mfb  = murT + (size_t)yy * NTOK * HEADS + H;

  float4 acc0 = {0,0,0,0}, acc1 = {0,0,0,0}, acc2 = {0,0,0,0}, acc3 = {0,0,0,0};
  float den = 0.f, cc = 0.f;

  #pragma unroll 2
  for (int ia = 0; ia < 6; ++ia) {
    const int a = ia * 16 + da;
    const float4* fp = (const float4*)(fbase + (size_t)a * EMBED);
    const float4 f0 = fp[0], f1 = fp[1], f2 = fp[2], f3 = fp[3];
    const float4 mrF = mfb[(size_t)a * HEADS];
    const float4 mrE = mur_sm[a];
    const float4 e0 = *(const float4*)&e_sm[a][eoff];
    const float4 e1 = *(const float4*)&e_sm[a][eoff + 4];
    const float4 e2 = *(const float4*)&e_sm[a][eoff + 8];
    const float4 e3 = *(const float4*)&e_sm[a][eoff + 12];

    float sraw = 0.f, m = 0.f, q = 0.f;
    float4 t0, t1, t2, t3;
    PR_QUAD(e0, f0, g2q0, t0);
    PR_QUAD(e1, f1, g2q1, t1);
    PR_QUAD(e2, f2, g2q2, t2);
    PR_QUAD(e3, f3, g2q3, t3);

    // combine d-halves (xor ds bit)
    sraw += __shfl_xor(sraw, 16, 64);
    m    += __shfl_xor(m,    16, 64);
    q    += __shfl_xor(q,    16, 64);

    // LN'd score from raw moments
    const float muE = mrE.x, rE = mrE.y, Sg2E = mrE.z, SgbE = mrE.w;
    const float muF = mrF.x, rF = mrF.y, Sg2F = mrF.z, SgbF = mrF.w;
    const float inner = sraw - muF * Sg2E - muE * Sg2F + muE * muF * T2c;
    const float sfull = rE * rF * inner
                      + rE * (SgbE - muE * Vbc)
                      + rF * (SgbF - muF * Vbc) + Wbc;
    const float sc = sfull * 0.17677669529663687f;   // 1/sqrt(32)

    // product-LN stats
    const float mu = m * (1.f / HD);
    const float var = fmaxf(fmaf(-mu, mu, q * (1.f / HD)), 0.f);
    const float r = rsqrtf(var + 1e-5f);

    const float ex = __expf(sc - SB);   // <= 1 by construction
    const float w = ex * r;
    den += ex;
    cc  = fmaf(w, mu, cc);
    AGG_QUAD(acc0, t0);
    AGG_QUAD(acc1, t1);
    AGG_QUAD(acc2, t2);
    AGG_QUAD(acc3, t3);
  }

  // cross-a reduction over the 16 da lanes
  #pragma unroll
  for (int mask = 1; mask <= 8; mask <<= 1) {
    den += __shfl_xor(den, mask, 64);
    cc  += __shfl_xor(cc,  mask, 64);
    RED_QUAD(acc0, mask);
    RED_QUAD(acc1, mask);
    RED_QUAD(acc2, mask);
    RED_QUAD(acc3, mask);
  }

  if (da == 0) {
    const float4 gq0 = *(const float4*)&ln_g[eoff];
    const float4 gq1 = *(const float4*)&ln_g[eoff + 4];
    const float4 gq2 = *(const float4*)&ln_g[eoff + 8];
    const float4 gq3 = *(const float4*)&ln_g[eoff + 12];
    const float4 bq0 = *(const float4*)&ln_b[eoff];
    const float4 bq1 = *(const float4*)&ln_b[eoff + 4];
    const float4 bq2 = *(const float4*)&ln_b[eoff + 8];
    const float4 bq3 = *(const float4*)&ln_b[eoff + 12];
    const float inv = 1.f / den;
    float4 o0, o1, o2, o3;
    o0.x = fmaf(gq0.x, (acc0.x - cc) * inv, bq0.x);
    o0.y = fmaf(gq0.y, (acc0.y - cc) * inv, bq0.y);
    o0.z = fmaf(gq0.z, (acc0.z - cc) * inv, bq0.z);
    o0.w = fmaf(gq0.w, (acc0.w - cc) * inv, bq0.w);
    o1.x = fmaf(gq1.x, (acc1.x - cc) * inv, bq1.x);
    o1.y = fmaf(gq1.y, (acc1.y - cc) * inv, bq1.y);
    o1.z = fmaf(gq1.z, (acc1.z - cc) * inv, bq1.z);
    o1.w = fmaf(gq1.w, (acc1.w - cc) * inv, bq1.w);
    o2.x = fmaf(gq2.x, (acc2.x - cc) * inv, bq2.x);
    o2.y = fmaf(gq2.y, (acc2.y - cc) * inv, bq2.y);
    o2.z = fmaf(gq2.z, (acc2.z - cc) * inv, bq2.z);
    o2.w = fmaf(gq2.w, (acc2.w - cc) * inv, bq2.w);
    o3.x = fmaf(gq3.x, (acc3.x - cc) * inv, bq3.x);
    o3.y = fmaf(gq3.y, (acc3.y - cc) * inv, bq3.y);
    o3.z = fmaf(gq3.z, (acc3.z - cc) * inv, bq3.z);
    o3.w = fmaf(gq3.w, (acc3.w - cc) * inv, bq3.w);
    float* op = agg + ((size_t)(X * NTOK + yy)) * EMBED + H * HD + eoff;
    *(float4*)&op[0]  = o0;
    *(float4*)&op[4]  = o1;
    *(float4*)&op[8]  = o2;
    *(float4*)&op[12] = o3;
  }
}

// ---- K3: out = LN([x, agg] @ Wf + bf) ----
// 1152 blocks x 256 threads, 8 rows per block
__global__ __launch_bounds__(256) void k_final(
    const float* __restrict__ x, const float* __restrict__ agg,
    const float* __restrict__ Wf, const float* __restrict__ bf,
    const float* __restrict__ g2, const float* __restrict__ b2,
    float* __restrict__ out) {
  const int r0 = blockIdx.x * 8;
  const int tid = threadIdx.x;
  const int e = tid & 127;
  const int rh = tid >> 7;               // rows rh*4 .. rh*4+3
  __shared__ float ct[2 * EMBED][12];    // transposed [x|agg], 12.3 KB
  __shared__ float red_sm[4][4][2];

  #pragma unroll
  for (int i = 0; i < 8; ++i) {
    const int g = tid + i * 256;         // 0..2047
    const int yl = g >> 8, col = g & 255;
    const size_t row = (size_t)(r0 + yl);
    const float v = (col < 128) ? x[row * EMBED + col]
                                : agg[row * EMBED + (col - 128)];
    ct[col][yl] = v;
  }
  __syncthreads();

  const float bias = bf[e];
  float acc4[4] = {bias, bias, bias, bias};
  #pragma unroll 8
  for (int i = 0; i < 2 * EMBED; ++i) {
    const float wv = Wf[(size_t)i * EMBED + e];
    const float4 c0 = *(const float4*)&ct[i][rh * 4];
    acc4[0] = fmaf(wv, c0.x, acc4[0]); acc4[1] = fmaf(wv, c0.y, acc4[1]);
    acc4[2] = fmaf(wv, c0.z, acc4[2]); acc4[3] = fmaf(wv, c0.w, acc4[3]);
  }

  const int wid = tid >> 6;
  #pragma unroll
  for (int k = 0; k < 4; ++k) {
    float s1 = acc4[k], s2 = acc4[k] * acc4[k];
    #pragma unroll
    for (int m_ = 1; m_ < 64; m_ <<= 1) {
      s1 += __shfl_xor(s1, m_, 64);
      s2 += __shfl_xor(s2, m_, 64);
    }
    if ((tid & 63) == 0) { red_sm[wid][k][0] = s1; red_sm[wid][k][1] = s2; }
  }
  __syncthreads();

  const float gg = g2[e], bb = b2[e];
  #pragma unroll
  for (int k = 0; k < 4; ++k) {
    const float S1 = red_sm[wid][k][0] + red_sm[wid ^ 1][k][0];
    const float S2 = red_sm[wid][k][1] + red_sm[wid ^ 1][k][1];
    const float mu = S1 * (1.f / EMBED);
    const float var = fmaxf(S2 * (1.f / EMBED) - mu * mu, 0.f);
    const float rstd = rsqrtf(var + 1e-5f);
    out[(size_t)(r0 + rh * 4 + k) * EMBED + e] = (acc4[k] - mu) * rstd * gg + bb;
  }
}

extern "C" void kernel_launch(void* const* d_in, const int* in_sizes, int n_in,
                              void* d_out, int out_size, void* d_ws, size_t ws_size,
                              hipStream_t stream) {
  const float* x    = (const float*)d_in[0];
  const float* W    = (const float*)d_in[1];
  const float* b    = (const float*)d_in[2];
  const float* ln_g = (const float*)d_in[3];
  const float* ln_b = (const float*)d_in[4];
  const float* Wf   = (const float*)d_in[5];
  const float* bf   = (const float*)d_in[6];
  const float* g2   = (const float*)d_in[7];
  const float* b2   = (const float*)d_in[8];
  float* out = (float*)d_out;

  float*  pT   = (float*)d_ws;                        // NROW*128 floats
  float4* murT = (float4*)(pT + (size_t)NROW * EMBED);// NROW*4 float4
  float*  agg  = (float*)(murT + (size_t)NROW * HEADS);

  k_proj<<<NROW / 4, 128, 0, stream>>>(x, W, b, ln_g, ln_b, pT, murT);
  k_attn<<<NTOK * NYT * HEADS, 256, 0, stream>>>(pT, murT, ln_g, ln_b, agg);
  k_final<<<NROW / 8, 256, 0, stream>>>(x, agg, Wf, bf, g2, b2, out);
}

// Round 11
// 110.967 us; speedup vs baseline: 2.1152x; 1.0136x over previous
//
#include <hip/hip_runtime.h>
#include <math.h>

#define NTOK 96
#define EMBED 128
#define HEADS 4
#define HD 32
#define NROW (NTOK*NTOK)     // 9216
#define YT 8
#define NYT (NTOK/YT)        // 12

// ---- K1: head-major projection ----
// pF[v][h][u][32] = head-h slice of p(u,v);  murF[v][h][u] = {mu,rstd,Sg2,Sgb}
// 2304 blocks x 128 threads, 4 rows per block
__global__ __launch_bounds__(128) void k_proj(
    const float* __restrict__ x, const float* __restrict__ W,
    const float* __restrict__ b, const float* __restrict__ ln_g,
    const float* __restrict__ ln_b,
    float* __restrict__ pF, float4* __restrict__ murF) {
  const int r0 = blockIdx.x * 4;         // global row = u*96 + v
  const int U  = r0 / NTOK;
  const int v0 = r0 % NTOK;
  const int e  = threadIdx.x;            // 0..127
  __shared__ float xt[EMBED][4];
  #pragma unroll
  for (int k = 0; k < 4; ++k)
    xt[e][k] = x[(size_t)(r0 + k) * EMBED + e];
  __syncthreads();

  const float bias = b[e];
  float a0 = bias, a1 = bias, a2 = bias, a3 = bias;
  #pragma unroll 8
  for (int i = 0; i < EMBED; ++i) {
    const float wv = W[(size_t)i * EMBED + e];
    const float4 c = *(const float4*)&xt[i][0];
    a0 = fmaf(wv, c.x, a0); a1 = fmaf(wv, c.y, a1);
    a2 = fmaf(wv, c.z, a2); a3 = fmaf(wv, c.w, a3);
  }

  const int h = e >> 5;
  const int d = e & 31;
  const float gl = ln_g[d];
  const float bl = ln_b[d];
  const float gl2 = gl * gl;
  const float gvb = gl * bl;
  float accs[4] = {a0, a1, a2, a3};
  #pragma unroll
  for (int k = 0; k < 4; ++k) {
    const float val = accs[k];
    const int v = v0 + k;
    pF[(((size_t)v * HEADS + h) * NTOK + U) * HD + d] = val;
    float s1 = val, s2 = val * val, s3 = gl2 * val, s4 = gvb * val;
    #pragma unroll
    for (int m_ = 1; m_ < 32; m_ <<= 1) {
      s1 += __shfl_xor(s1, m_, 64);
      s2 += __shfl_xor(s2, m_, 64);
      s3 += __shfl_xor(s3, m_, 64);
      s4 += __shfl_xor(s4, m_, 64);
    }
    if (d == 0) {
      const float mu = s1 * (1.f / HD);
      const float var = fmaxf(s2 * (1.f / HD) - mu * mu, 0.f);
      float4 o; o.x = mu; o.y = rsqrtf(var + 1e-5f); o.z = s3; o.w = s4;
      murF[((size_t)v * HEADS + h) * NTOK + U] = o;
    }
  }
}

#define PR_QUAD(E4, F4, G2, T4) \
  T4.x = E4.x * F4.x; sraw = fmaf(G2.x, T4.x, sraw); m += T4.x; q = fmaf(T4.x, T4.x, q); \
  T4.y = E4.y * F4.y; sraw = fmaf(G2.y, T4.y, sraw); m += T4.y; q = fmaf(T4.y, T4.y, q); \
  T4.z = E4.z * F4.z; sraw = fmaf(G2.z, T4.z, sraw); m += T4.z; q = fmaf(T4.z, T4.z, q); \
  T4.w = E4.w * F4.w; sraw = fmaf(G2.w, T4.w, sraw); m += T4.w; q = fmaf(T4.w, T4.w, q);

#define AGG_QUAD(A4, T4) \
  A4.x = fmaf(w, T4.x, A4.x); A4.y = fmaf(w, T4.y, A4.y); \
  A4.z = fmaf(w, T4.z, A4.z); A4.w = fmaf(w, T4.w, A4.w);

#define RED_QUAD(A4, MASK) \
  A4.x += __shfl_xor(A4.x, MASK, 64); A4.y += __shfl_xor(A4.y, MASK, 64); \
  A4.z += __shfl_xor(A4.z, MASK, 64); A4.w += __shfl_xor(A4.w, MASK, 64);

// ---- K2: attention + product-LN aggregation, one head per block ----
// 4608 blocks (X fastest; then yt:12, h:4) x 256 threads = (y:8, ds:2, da:16)
// f-stream now DENSE: pF[yy][H][a][.] contiguous in a (128 B per a).
__global__ __launch_bounds__(256) void k_attn(
    const float* __restrict__ pF, const float4* __restrict__ murF,
    const float* __restrict__ ln_g, const float* __restrict__ ln_b,
    float* __restrict__ agg) {
  const int bid = blockIdx.x;
  const int X   = bid % NTOK;
  const int t2i = bid / NTOK;            // 0..47
  const int y0  = (t2i % NYT) * YT;
  const int H   = t2i / NYT;

  const int tid = threadIdx.x;
  const int y   = tid >> 5;            // 0..7
  const int ds  = (tid >> 4) & 1;      // d-half
  const int da  = tid & 15;            // a-slice
  const int yy  = y0 + y;
  const int eoff = ds * 16;

  __shared__ float e_sm[NTOK][36];     // 13.8 KB
  __shared__ float4 mur_sm[NTOK];      // 1.5 KB

  // stage e-side: e[a] = p(X,a) = pF[a][H][X][.]  (scattered, once per block)
  #pragma unroll
  for (int i = 0; i < 3; ++i) {
    const int g = tid + i * 256;       // 0..767
    const int a = g >> 3, qq = g & 7;
    *(float4*)&e_sm[a][qq * 4] =
        *(const float4*)&pF[(((size_t)a * HEADS + H) * NTOK + X) * HD + qq * 4];
  }
  if (tid < NTOK)
    mur_sm[tid] = murF[((size_t)tid * HEADS + H) * NTOK + X];

  // LN constants: T2=sum g^2, Vb=sum g*b, Wb=sum b^2, Mg2=max g^2
  const float glx = ln_g[tid & 31];
  const float blx = ln_b[tid & 31];
  float T2c = glx * glx, Vbc = glx * blx, Wbc = blx * blx, Mg2 = glx * glx;
  #pragma unroll
  for (int m_ = 1; m_ < 32; m_ <<= 1) {
    T2c += __shfl_xor(T2c, m_, 64);
    Vbc += __shfl_xor(Vbc, m_, 64);
    Wbc += __shfl_xor(Wbc, m_, 64);
    Mg2 = fmaxf(Mg2, __shfl_xor(Mg2, m_, 64));
  }
  // score bound: |sc| <= (64*Mg2 + 2*Wb) / sqrt(32)
  const float SB = (64.f * Mg2 + 2.f * Wbc) * 0.17677669529663687f;

  // g^2 weights for this lane's d-range (not kept live; reloaded in epilogue)
  float4 g2q0, g2q1, g2q2, g2q3;
  {
    const float4 t0 = *(const float4*)&ln_g[eoff];
    const float4 t1 = *(const float4*)&ln_g[eoff + 4];
    const float4 t2 = *(const float4*)&ln_g[eoff + 8];
    const float4 t3 = *(const float4*)&ln_g[eoff + 12];
    g2q0.x = t0.x*t0.x; g2q0.y = t0.y*t0.y; g2q0.z = t0.z*t0.z; g2q0.w = t0.w*t0.w;
    g2q1.x = t1.x*t1.x; g2q1.y = t1.y*t1.y; g2q1.z = t1.z*t1.z; g2q1.w = t1.w*t1.w;
    g2q2.x = t2.x*t2.x; g2q2.y = t2.y*t2.y; g2q2.z = t2.z*t2.z; g2q2.w = t2.w*t2.w;
    g2q3.x = t3.x*t3.x; g2q3.y = t3.y*t3.y; g2q3.z = t3.z*t3.z; g2q3.w = t3.w*t3.w;
  }
  __syncthreads();

  // dense f-stream: pF[yy][H][a][.]  and murF[yy][H][a]
  const float* fbase = pF + (((size_t)yy * HEADS + H) * NTOK) * HD + eoff;
  const float4* mfb  = murF + ((size_t)yy * HEADS + H) * NTOK;

  float4 acc0 = {0,0,0,0}, acc1 = {0,0,0,0}, acc2 = {0,0,0,0}, acc3 = {0,0,0,0};
  float den = 0.f, cc = 0.f;

  #pragma unroll 2
  for (int ia = 0; ia < 6; ++ia) {
    const int a = ia * 16 + da;
    const float4* fp = (const float4*)(fbase + (size_t)a * HD);
    const float4 f0 = fp[0], f1 = fp[1], f2 = fp[2], f3 = fp[3];
    const float4 mrF = mfb[a];
    const float4 mrE = mur_sm[a];
    const float4 e0 = *(const float4*)&e_sm[a][eoff];
    const float4 e1 = *(const float4*)&e_sm[a][eoff + 4];
    const float4 e2 = *(const float4*)&e_sm[a][eoff + 8];
    const float4 e3 = *(const float4*)&e_sm[a][eoff + 12];

    float sraw = 0.f, m = 0.f, q = 0.f;
    float4 t0, t1, t2, t3;
    PR_QUAD(e0, f0, g2q0, t0);
    PR_QUAD(e1, f1, g2q1, t1);
    PR_QUAD(e2, f2, g2q2, t2);
    PR_QUAD(e3, f3, g2q3, t3);

    // combine d-halves (xor ds bit)
    sraw += __shfl_xor(sraw, 16, 64);
    m    += __shfl_xor(m,    16, 64);
    q    += __shfl_xor(q,    16, 64);

    // LN'd score from raw moments
    const float muE = mrE.x, rE = mrE.y, Sg2E = mrE.z, SgbE = mrE.w;
    const float muF = mrF.x, rF = mrF.y, Sg2F = mrF.z, SgbF = mrF.w;
    const float inner = sraw - muF * Sg2E - muE * Sg2F + muE * muF * T2c;
    const float sfull = rE * rF * inner
                      + rE * (SgbE - muE * Vbc)
                      + rF * (SgbF - muF * Vbc) + Wbc;
    const float sc = sfull * 0.17677669529663687f;   // 1/sqrt(32)

    // product-LN stats
    const float mu = m * (1.f / HD);
    const float var = fmaxf(fmaf(-mu, mu, q * (1.f / HD)), 0.f);
    const float r = rsqrtf(var + 1e-5f);

    const float ex = __expf(sc - SB);   // <= 1 by construction
    const float w = ex * r;
    den += ex;
    cc  = fmaf(w, mu, cc);
    AGG_QUAD(acc0, t0);
    AGG_QUAD(acc1, t1);
    AGG_QUAD(acc2, t2);
    AGG_QUAD(acc3, t3);
  }

  // cross-a reduction over the 16 da lanes
  #pragma unroll
  for (int mask = 1; mask <= 8; mask <<= 1) {
    den += __shfl_xor(den, mask, 64);
    cc  += __shfl_xor(cc,  mask, 64);
    RED_QUAD(acc0, mask);
    RED_QUAD(acc1, mask);
    RED_QUAD(acc2, mask);
    RED_QUAD(acc3, mask);
  }

  if (da == 0) {
    const float4 gq0 = *(const float4*)&ln_g[eoff];
    const float4 gq1 = *(const float4*)&ln_g[eoff + 4];
    const float4 gq2 = *(const float4*)&ln_g[eoff + 8];
    const float4 gq3 = *(const float4*)&ln_g[eoff + 12];
    const float4 bq0 = *(const float4*)&ln_b[eoff];
    const float4 bq1 = *(const float4*)&ln_b[eoff + 4];
    const float4 bq2 = *(const float4*)&ln_b[eoff + 8];
    const float4 bq3 = *(const float4*)&ln_b[eoff + 12];
    const float inv = 1.f / den;
    float4 o0, o1, o2, o3;
    o0.x = fmaf(gq0.x, (acc0.x - cc) * inv, bq0.x);
    o0.y = fmaf(gq0.y, (acc0.y - cc) * inv, bq0.y);
    o0.z = fmaf(gq0.z, (acc0.z - cc) * inv, bq0.z);
    o0.w = fmaf(gq0.w, (acc0.w - cc) * inv, bq0.w);
    o1.x = fmaf(gq1.x, (acc1.x - cc) * inv, bq1.x);
    o1.y = fmaf(gq1.y, (acc1.y - cc) * inv, bq1.y);
    o1.z = fmaf(gq1.z, (acc1.z - cc) * inv, bq1.z);
    o1.w = fmaf(gq1.w, (acc1.w - cc) * inv, bq1.w);
    o2.x = fmaf(gq2.x, (acc2.x - cc) * inv, bq2.x);
    o2.y = fmaf(gq2.y, (acc2.y - cc) * inv, bq2.y);
    o2.z = fmaf(gq2.z, (acc2.z - cc) * inv, bq2.z);
    o2.w = fmaf(gq2.w, (acc2.w - cc) * inv, bq2.w);
    o3.x = fmaf(gq3.x, (acc3.x - cc) * inv, bq3.x);
    o3.y = fmaf(gq3.y, (acc3.y - cc) * inv, bq3.y);
    o3.z = fmaf(gq3.z, (acc3.z - cc) * inv, bq3.z);
    o3.w = fmaf(gq3.w, (acc3.w - cc) * inv, bq3.w);
    float* op = agg + ((size_t)(X * NTOK + yy)) * EMBED + H * HD + eoff;
    *(float4*)&op[0]  = o0;
    *(float4*)&op[4]  = o1;
    *(float4*)&op[8]  = o2;
    *(float4*)&op[12] = o3;
  }
}

// ---- K3: out = LN([x, agg] @ Wf + bf) ----
// 1152 blocks x 256 threads, 8 rows per block
__global__ __launch_bounds__(256) void k_final(
    const float* __restrict__ x, const float* __restrict__ agg,
    const float* __restrict__ Wf, const float* __restrict__ bf,
    const float* __restrict__ g2, const float* __restrict__ b2,
    float* __restrict__ out) {
  const int r0 = blockIdx.x * 8;
  const int tid = threadIdx.x;
  const int e = tid & 127;
  const int rh = tid >> 7;               // rows rh*4 .. rh*4+3
  __shared__ float ct[2 * EMBED][12];    // transposed [x|agg], 12.3 KB
  __shared__ float red_sm[4][4][2];

  #pragma unroll
  for (int i = 0; i < 8; ++i) {
    const int g = tid + i * 256;         // 0..2047
    const int yl = g >> 8, col = g & 255;
    const size_t row = (size_t)(r0 + yl);
    const float v = (col < 128) ? x[row * EMBED + col]
                                : agg[row * EMBED + (col - 128)];
    ct[col][yl] = v;
  }
  __syncthreads();

  const float bias = bf[e];
  float acc4[4] = {bias, bias, bias, bias};
  #pragma unroll 8
  for (int i = 0; i < 2 * EMBED; ++i) {
    const float wv = Wf[(size_t)i * EMBED + e];
    const float4 c0 = *(const float4*)&ct[i][rh * 4];
    acc4[0] = fmaf(wv, c0.x, acc4[0]); acc4[1] = fmaf(wv, c0.y, acc4[1]);
    acc4[2] = fmaf(wv, c0.z, acc4[2]); acc4[3] = fmaf(wv, c0.w, acc4[3]);
  }

  const int wid = tid >> 6;
  #pragma unroll
  for (int k = 0; k < 4; ++k) {
    float s1 = acc4[k], s2 = acc4[k] * acc4[k];
    #pragma unroll
    for (int m_ = 1; m_ < 64; m_ <<= 1) {
      s1 += __shfl_xor(s1, m_, 64);
      s2 += __shfl_xor(s2, m_, 64);
    }
    if ((tid & 63) == 0) { red_sm[wid][k][0] = s1; red_sm[wid][k][1] = s2; }
  }
  __syncthreads();

  const float gg = g2[e], bb = b2[e];
  #pragma unroll
  for (int k = 0; k < 4; ++k) {
    const float S1 = red_sm[wid][k][0] + red_sm[wid ^ 1][k][0];
    const float S2 = red_sm[wid][k][1] + red_sm[wid ^ 1][k][1];
    const float mu = S1 * (1.f / EMBED);
    const float var = fmaxf(S2 * (1.f / EMBED) - mu * mu, 0.f);
    const float rstd = rsqrtf(var + 1e-5f);
    out[(size_t)(r0 + rh * 4 + k) * EMBED + e] = (acc4[k] - mu) * rstd * gg + bb;
  }
}

extern "C" void kernel_launch(void* const* d_in, const int* in_sizes, int n_in,
                              void* d_out, int out_size, void* d_ws, size_t ws_size,
                              hipStream_t stream) {
  const float* x    = (const float*)d_in[0];
  const float* W    = (const float*)d_in[1];
  const float* b    = (const float*)d_in[2];
  const float* ln_g = (const float*)d_in[3];
  const float* ln_b = (const float*)d_in[4];
  const float* Wf   = (const float*)d_in[5];
  const float* bf   = (const float*)d_in[6];
  const float* g2   = (const float*)d_in[7];
  const float* b2   = (const float*)d_in[8];
  float* out = (float*)d_out;

  float*  pF   = (float*)d_ws;                         // NROW*128 floats
  float4* murF = (float4*)(pF + (size_t)NROW * EMBED); // NROW*4 float4
  float*  agg  = (float*)(murF + (size_t)NROW * HEADS);

  k_proj<<<NROW / 4, 128, 0, stream>>>(x, W, b, ln_g, ln_b, pF, murF);
  k_attn<<<NTOK * NYT * HEADS, 256, 0, stream>>>(pF, murF, ln_g, ln_b, agg);
  k_final<<<NROW / 8, 256, 0, stream>>>(x, agg, Wf, bf, g2, b2, out);
}